// Round 2
// baseline (404.506 us; speedup 1.0000x reference)
//
#include <hip/hip_runtime.h>

#define TOK   65536
#define HID   768
#define NSEQ  128
#define FFD   3072
#define PCH   32               // tokens per pool chunk (min seg len >= 34 -> <=1 boundary/chunk)
#define NPCH  (TOK / PCH)      // 2048 blocks
#define KS1   8
#define KCH1  96               // 8 * 96  = 768
#define KS2   32
#define KCH2  96               // 32 * 96 = 3072
#define ZF4   (NSEQ * (FFD + HID) / 4)   // float4s to zero (h1 + outacc), 122880

__device__ __forceinline__ void add4(float4& a, const float4 b) {
  a.x += b.x; a.y += b.y; a.z += b.z; a.w += b.w;
}

// Hillis-Steele inclusive scan of lens[] into sc[] (block-wide, >=128 threads).
__device__ __forceinline__ void scan_lens(const int* __restrict__ lens, int* sc, int tid) {
  if (tid < NSEQ) sc[tid] = lens[tid];
  __syncthreads();
  for (int off = 1; off < NSEQ; off <<= 1) {
    int v = 0;
    if (tid < NSEQ && tid >= off) v = sc[tid - off];
    __syncthreads();
    if (tid < NSEQ) sc[tid] += v;
    __syncthreads();
  }
}

// Phase 1 of pooling: per-chunk partial sums, NO atomics.
// Also zero-fills the h1/outacc accumulators (rides free under the BW-bound read).
__global__ __launch_bounds__(192, 6) void pool_part(
    const float* __restrict__ x, const int* __restrict__ lens,
    float* __restrict__ plo, float* __restrict__ phi,
    float* __restrict__ zbuf) {
  __shared__ int sc[NSEQ];
  const int tid = threadIdx.x;
  // accumulator zeroing: one float4 store for the first ZF4 global threads
  const size_t gtid = (size_t)blockIdx.x * 192 + tid;
  if (gtid < ZF4) ((float4*)zbuf)[gtid] = make_float4(0.f, 0.f, 0.f, 0.f);
  scan_lens(lens, sc, tid);
  const int t0 = blockIdx.x * PCH;
  int lo = 0, hi = NSEQ - 1;                   // first seg with incl cumsum > t0
  while (lo < hi) { int mid = (lo + hi) >> 1; if (sc[mid] <= t0) lo = mid + 1; else hi = mid; }
  const int segend = sc[lo];
  const float4* p = (const float4*)x + (size_t)t0 * (HID / 4) + tid;
  float4* dlo = (float4*)plo + (size_t)blockIdx.x * (HID / 4) + tid;

  if (segend >= t0 + PCH) {
    // fast path: whole chunk in one segment; 32 independent loads
    float4 a0 = make_float4(0.f,0.f,0.f,0.f), a1 = a0, a2 = a0, a3 = a0;
    #pragma unroll
    for (int i = 0; i < PCH; i += 4) {
      add4(a0, p[(size_t)(i+0) * (HID/4)]);
      add4(a1, p[(size_t)(i+1) * (HID/4)]);
      add4(a2, p[(size_t)(i+2) * (HID/4)]);
      add4(a3, p[(size_t)(i+3) * (HID/4)]);
    }
    add4(a0, a1); add4(a2, a3); add4(a0, a2);
    *dlo = a0;
  } else {
    // boundary chunk (~6%): two runs, write both partial rows
    const int n0 = segend - t0;                // 1..31
    float4 a0 = make_float4(0.f,0.f,0.f,0.f), a1 = a0;
    for (int i = 0;  i < n0;  ++i) add4(a0, p[(size_t)i * (HID/4)]);
    for (int i = n0; i < PCH; ++i) add4(a1, p[(size_t)i * (HID/4)]);
    *dlo = a0;
    *((float4*)phi + (size_t)blockIdx.x * (HID/4) + tid) = a1;
  }
}

// Phase 2: one block per segment sums its chunk partials (deterministic) and divides by len.
__global__ __launch_bounds__(192) void pool_reduce(
    const int* __restrict__ lens, const float* __restrict__ plo,
    const float* __restrict__ phi, float* __restrict__ pooled) {
  __shared__ int sc[NSEQ];
  const int tid = threadIdx.x;
  scan_lens(lens, sc, tid);
  const int s = blockIdx.x;
  const int st = s ? sc[s - 1] : 0;
  const int en = sc[s];
  const int c0 = st >> 5, c1 = (en - 1) >> 5;  // chunk range overlapping segment s
  const float4* lo4 = (const float4*)plo;
  const float4* hi4 = (const float4*)phi;
  float4 acc = make_float4(0.f,0.f,0.f,0.f);
  for (int c = c0; c <= c1; ++c) {
    // first chunk is a tail run (part_hi) iff the segment starts mid-chunk
    const float4* src = (c == c0 && (st & (PCH - 1))) ? hi4 : lo4;
    add4(acc, src[(size_t)c * (HID / 4) + tid]);
  }
  const float inv = 1.0f / (float)(en - st);
  float4 r;
  r.x = acc.x * inv; r.y = acc.y * inv; r.z = acc.z * inv; r.w = acc.w * inv;
  ((float4*)pooled)[(size_t)s * (HID / 4) + tid] = r;
}

// C[128 x N] += A[128 x Kt] * B[N x Kt]^T over this ksplit's k-range (atomic fold).
// Tile 128s x 32f, 256 threads, thread tile 4s x 4f. Register-prefetch pipeline:
// chunk c+1's global loads issue while chunk c computes from LDS.
__global__ __launch_bounds__(256) void gemm_nt(
    const float* __restrict__ A, const float* __restrict__ B,
    float* __restrict__ C, int N, int Kt, int kch) {
  __shared__ float As[16][132];   // [k][s], 2-way max bank alias (free)
  __shared__ float Bs[16][36];    // [k][f]

  const int tid = threadIdx.x;
  const int f0 = blockIdx.x * 32;
  const int k0 = blockIdx.y * kch;
  const int fx = (tid & 7) * 4;
  const int sy = (tid >> 3) * 4;
  const int sA = tid >> 2;                     // A row for r=0 (r=1 -> +64)
  const int kA = (tid & 3) * 4;                // k offset within chunk
  const int fB = tid >> 2;                     // B row (tid<128 only)

  const float* pA0 = A + (size_t)sA * Kt + k0 + kA;
  const float* pA1 = pA0 + (size_t)64 * Kt;
  const float* pB  = B + (size_t)(f0 + fB) * Kt + k0 + kA;

  float4 va0 = *(const float4*)pA0;
  float4 va1 = *(const float4*)pA1;
  float4 vb = make_float4(0.f,0.f,0.f,0.f);
  if (tid < 128) vb = *(const float4*)pB;

  float acc[4][4];
  #pragma unroll
  for (int i = 0; i < 4; ++i)
    #pragma unroll
    for (int j = 0; j < 4; ++j) acc[i][j] = 0.f;

  const int nch = kch >> 4;
  for (int c = 0; c < nch; ++c) {
    // write staged registers -> LDS (k-major transpose scatter, 2-way alias max)
    As[kA + 0][sA]      = va0.x; As[kA + 1][sA]      = va0.y;
    As[kA + 2][sA]      = va0.z; As[kA + 3][sA]      = va0.w;
    As[kA + 0][sA + 64] = va1.x; As[kA + 1][sA + 64] = va1.y;
    As[kA + 2][sA + 64] = va1.z; As[kA + 3][sA + 64] = va1.w;
    if (tid < 128) {
      Bs[kA + 0][fB] = vb.x; Bs[kA + 1][fB] = vb.y;
      Bs[kA + 2][fB] = vb.z; Bs[kA + 3][fB] = vb.w;
    }
    __syncthreads();
    if (c + 1 < nch) {                         // prefetch next chunk during compute
      va0 = *(const float4*)(pA0 + (c + 1) * 16);
      va1 = *(const float4*)(pA1 + (c + 1) * 16);
      if (tid < 128) vb = *(const float4*)(pB + (c + 1) * 16);
    }
    #pragma unroll
    for (int kk = 0; kk < 16; ++kk) {
      const float4 aa = *(const float4*)&As[kk][sy];
      const float4 bb = *(const float4*)&Bs[kk][fx];
      acc[0][0] += aa.x*bb.x; acc[0][1] += aa.x*bb.y; acc[0][2] += aa.x*bb.z; acc[0][3] += aa.x*bb.w;
      acc[1][0] += aa.y*bb.x; acc[1][1] += aa.y*bb.y; acc[1][2] += aa.y*bb.z; acc[1][3] += aa.y*bb.w;
      acc[2][0] += aa.z*bb.x; acc[2][1] += aa.z*bb.y; acc[2][2] += aa.z*bb.z; acc[2][3] += aa.z*bb.w;
      acc[3][0] += aa.w*bb.x; acc[3][1] += aa.w*bb.y; acc[3][2] += aa.w*bb.z; acc[3][3] += aa.w*bb.w;
    }
    __syncthreads();
  }
  // atomic k-split fold directly into the (pre-zeroed) accumulator
  #pragma unroll
  for (int i = 0; i < 4; ++i) {
    float* dst = C + (size_t)(sy + i) * N + f0 + fx;
    atomicAdd(dst + 0, acc[i][0]);
    atomicAdd(dst + 1, acc[i][1]);
    atomicAdd(dst + 2, acc[i][2]);
    atomicAdd(dst + 3, acc[i][3]);
  }
}

// L2-normalize each row of the folded gemm2 accumulator.
__global__ __launch_bounds__(256) void norm_kernel(
    const float* __restrict__ h, float* __restrict__ out) {
  const int s = blockIdx.x;
  const int tid = threadIdx.x;
  float v[3];
  #pragma unroll
  for (int j = 0; j < 3; ++j) v[j] = h[(size_t)s * HID + tid + 256 * j];
  float ss = v[0]*v[0] + v[1]*v[1] + v[2]*v[2];
  #pragma unroll
  for (int off = 32; off > 0; off >>= 1) ss += __shfl_down(ss, off, 64);
  __shared__ float wsum[4];
  if ((tid & 63) == 0) wsum[tid >> 6] = ss;
  __syncthreads();
  const float tot = wsum[0] + wsum[1] + wsum[2] + wsum[3];
  const float scale = 1.0f / fmaxf(sqrtf(tot), 1e-12f);
  #pragma unroll
  for (int j = 0; j < 3; ++j) out[(size_t)s * HID + tid + 256 * j] = v[j] * scale;
}

extern "C" void kernel_launch(void* const* d_in, const int* in_sizes, int n_in,
                              void* d_out, int out_size, void* d_ws, size_t ws_size,
                              hipStream_t stream) {
  const float* x    = (const float*)d_in[0];  // [65536, 768]
  const int*   lens = (const int*)d_in[1];    // [128]
  const float* W1   = (const float*)d_in[2];  // [3072, 768]
  const float* W2   = (const float*)d_in[3];  // [768, 3072]
  float* out = (float*)d_out;                 // [128, 768]

  float* plo    = (float*)d_ws;                        // 2048*768
  float* phi    = plo + (size_t)NPCH * HID;            // 2048*768
  float* pooled = phi + (size_t)NPCH * HID;            // 128*768
  float* h1     = pooled + (size_t)NSEQ * HID;         // 128*3072  (atomic acc)
  float* outacc = h1 + (size_t)NSEQ * FFD;             // 128*768   (atomic acc)
  // h1 and outacc are contiguous -> single zero span written by pool_part

  pool_part<<<NPCH, 192, 0, stream>>>(x, lens, plo, phi, h1);
  pool_reduce<<<NSEQ, 192, 0, stream>>>(lens, plo, phi, pooled);
  gemm_nt<<<dim3(FFD / 32, KS1), 256, 0, stream>>>(pooled, W1, h1, FFD, HID, KCH1);
  gemm_nt<<<dim3(HID / 32, KS2), 256, 0, stream>>>(h1, W2, outacc, HID, FFD, KCH2);
  norm_kernel<<<NSEQ, 256, 0, stream>>>(outacc, out);
}

// Round 3
// 334.304 us; speedup vs baseline: 1.2100x; 1.2100x over previous
//
#include <hip/hip_runtime.h>

#define TOK   65536
#define HID   768
#define NSEQ  128
#define FFD   3072
#define PCH   32               // tokens per pool chunk (min seg len >= 34 -> <=1 boundary/chunk)
#define NPCH  (TOK / PCH)      // 2048 blocks
#define KS1   8
#define KCH1  96               // 8 * 96  = 768
#define KS2   24
#define KCH2  128              // 24 * 128 = 3072

__device__ __forceinline__ void add4(float4& a, const float4 b) {
  a.x += b.x; a.y += b.y; a.z += b.z; a.w += b.w;
}

// Segment mean-pool, built for HBM saturation: 2048 blocks x 192 threads
// (24 waves/CU), each block = 32 consecutive tokens, thread = one float4 col.
// Atomic fold into pooled[] is spread across the whole 30us BW-bound kernel
// (16 writers/line over ~30us) -> no serialization tail (R0-proven; the R2
// GEMM-epilogue atomics, 8-32 writers/line in ~5us, cost +59us -- density
// in time, not atomic count, is what matters).
__global__ __launch_bounds__(192, 6) void pool_kernel(
    const float* __restrict__ x, const int* __restrict__ lens,
    float* __restrict__ pooled) {
  __shared__ int sc[NSEQ];
  const int tid = threadIdx.x;
  if (tid < NSEQ) sc[tid] = lens[tid];
  __syncthreads();
  for (int off = 1; off < NSEQ; off <<= 1) {   // Hillis-Steele inclusive scan
    int v = 0;
    if (tid < NSEQ && tid >= off) v = sc[tid - off];
    __syncthreads();
    if (tid < NSEQ) sc[tid] += v;
    __syncthreads();
  }
  const int t0 = blockIdx.x * PCH;
  int lo = 0, hi = NSEQ - 1;                   // first seg with incl > t0
  while (lo < hi) { int mid = (lo + hi) >> 1; if (sc[mid] <= t0) lo = mid + 1; else hi = mid; }
  const int seg = lo;
  const int segend = sc[seg];
  const int segstart = seg ? sc[seg - 1] : 0;
  const float4* p = (const float4*)x + (size_t)t0 * (HID / 4) + tid;

  if (segend >= t0 + PCH) {
    // fast path: whole chunk in one segment; 32 independent loads
    float4 a0 = make_float4(0.f,0.f,0.f,0.f), a1 = a0, a2 = a0, a3 = a0;
    #pragma unroll
    for (int i = 0; i < PCH; i += 4) {
      add4(a0, p[(size_t)(i+0) * (HID/4)]);
      add4(a1, p[(size_t)(i+1) * (HID/4)]);
      add4(a2, p[(size_t)(i+2) * (HID/4)]);
      add4(a3, p[(size_t)(i+3) * (HID/4)]);
    }
    add4(a0, a1); add4(a2, a3); add4(a0, a2);
    const float inv = 1.0f / (float)(segend - segstart);
    float* dst = pooled + (size_t)seg * HID + tid * 4;
    atomicAdd(dst + 0, a0.x * inv);
    atomicAdd(dst + 1, a0.y * inv);
    atomicAdd(dst + 2, a0.z * inv);
    atomicAdd(dst + 3, a0.w * inv);
  } else {
    // boundary chunk (rare, ~6%): two runs
    const int n0 = segend - t0;                // 1..31
    float4 a0 = make_float4(0.f,0.f,0.f,0.f), a1 = a0;
    for (int i = 0; i < n0; ++i)  add4(a0, p[(size_t)i * (HID/4)]);
    for (int i = n0; i < PCH; ++i) add4(a1, p[(size_t)i * (HID/4)]);
    const float inv0 = 1.0f / (float)(segend - segstart);
    const float inv1 = 1.0f / (float)(sc[seg + 1] - segend);
    float* d0 = pooled + (size_t)seg * HID + tid * 4;
    atomicAdd(d0 + 0, a0.x * inv0);
    atomicAdd(d0 + 1, a0.y * inv0);
    atomicAdd(d0 + 2, a0.z * inv0);
    atomicAdd(d0 + 3, a0.w * inv0);
    float* d1 = pooled + (size_t)(seg + 1) * HID + tid * 4;
    atomicAdd(d1 + 0, a1.x * inv1);
    atomicAdd(d1 + 1, a1.y * inv1);
    atomicAdd(d1 + 2, a1.z * inv1);
    atomicAdd(d1 + 3, a1.w * inv1);
  }
}

// Cp[by][128 x N] = A[128 x Kt] * B[N x Kt]^T over this ksplit's k-range.
// Tile 128s x 32f, 256 threads, thread tile 4s x 4f. Register-prefetch
// pipeline: chunk c+1's global loads issue while chunk c computes from LDS.
__global__ __launch_bounds__(256) void gemm_nt(
    const float* __restrict__ A, const float* __restrict__ B,
    float* __restrict__ Cp, int N, int Kt, int kch) {
  __shared__ float As[16][132];   // [k][s], 2-way max bank alias (free)
  __shared__ float Bs[16][36];    // [k][f]

  const int tid = threadIdx.x;
  const int f0 = blockIdx.x * 32;
  const int k0 = blockIdx.y * kch;
  float* C = Cp + (size_t)blockIdx.y * NSEQ * N;
  const int fx = (tid & 7) * 4;
  const int sy = (tid >> 3) * 4;
  const int sA = tid >> 2;                     // A row for r=0 (r=1 -> +64)
  const int kA = (tid & 3) * 4;                // k offset within chunk
  const int fB = tid >> 2;                     // B row (tid<128 only)

  const float* pA0 = A + (size_t)sA * Kt + k0 + kA;
  const float* pA1 = pA0 + (size_t)64 * Kt;
  const float* pB  = B + (size_t)(f0 + fB) * Kt + k0 + kA;

  float4 va0 = *(const float4*)pA0;
  float4 va1 = *(const float4*)pA1;
  float4 vb = make_float4(0.f,0.f,0.f,0.f);
  if (tid < 128) vb = *(const float4*)pB;

  float acc[4][4];
  #pragma unroll
  for (int i = 0; i < 4; ++i)
    #pragma unroll
    for (int j = 0; j < 4; ++j) acc[i][j] = 0.f;

  const int nch = kch >> 4;
  for (int c = 0; c < nch; ++c) {
    // write staged registers -> LDS (k-major transpose scatter, 2-way alias max)
    As[kA + 0][sA]      = va0.x; As[kA + 1][sA]      = va0.y;
    As[kA + 2][sA]      = va0.z; As[kA + 3][sA]      = va0.w;
    As[kA + 0][sA + 64] = va1.x; As[kA + 1][sA + 64] = va1.y;
    As[kA + 2][sA + 64] = va1.z; As[kA + 3][sA + 64] = va1.w;
    if (tid < 128) {
      Bs[kA + 0][fB] = vb.x; Bs[kA + 1][fB] = vb.y;
      Bs[kA + 2][fB] = vb.z; Bs[kA + 3][fB] = vb.w;
    }
    __syncthreads();
    if (c + 1 < nch) {                         // prefetch next chunk during compute
      va0 = *(const float4*)(pA0 + (c + 1) * 16);
      va1 = *(const float4*)(pA1 + (c + 1) * 16);
      if (tid < 128) vb = *(const float4*)(pB + (c + 1) * 16);
    }
    #pragma unroll
    for (int kk = 0; kk < 16; ++kk) {
      const float4 aa = *(const float4*)&As[kk][sy];
      const float4 bb = *(const float4*)&Bs[kk][fx];
      acc[0][0] += aa.x*bb.x; acc[0][1] += aa.x*bb.y; acc[0][2] += aa.x*bb.z; acc[0][3] += aa.x*bb.w;
      acc[1][0] += aa.y*bb.x; acc[1][1] += aa.y*bb.y; acc[1][2] += aa.y*bb.z; acc[1][3] += aa.y*bb.w;
      acc[2][0] += aa.z*bb.x; acc[2][1] += aa.z*bb.y; acc[2][2] += aa.z*bb.z; acc[2][3] += aa.z*bb.w;
      acc[3][0] += aa.w*bb.x; acc[3][1] += aa.w*bb.y; acc[3][2] += aa.w*bb.z; acc[3][3] += aa.w*bb.w;
    }
    __syncthreads();
  }
  #pragma unroll
  for (int i = 0; i < 4; ++i)
    *(float4*)(C + (size_t)(sy + i) * N + f0 + fx) =
        make_float4(acc[i][0], acc[i][1], acc[i][2], acc[i][3]);
}

// h1 = sum of the KS1 gemm1 partial slabs. One float4 per thread.
__global__ __launch_bounds__(256) void reduce_h1(
    const float* __restrict__ h1p, float* __restrict__ h1) {
  const size_t i = (size_t)blockIdx.x * 256 + threadIdx.x;  // < 98304 float4s
  const float4* src = (const float4*)h1p;
  float4 a = src[i];
  #pragma unroll
  for (int p = 1; p < KS1; ++p) add4(a, src[i + (size_t)p * (NSEQ * FFD / 4)]);
  ((float4*)h1)[i] = a;
}

// Fold the KS2 gemm2 partials + L2 normalize each row.
__global__ __launch_bounds__(256) void norm_kernel(
    const float* __restrict__ outp, float* __restrict__ out) {
  const int s = blockIdx.x;
  const int tid = threadIdx.x;
  float v[3];
  #pragma unroll
  for (int j = 0; j < 3; ++j) {
    const int c = tid + 256 * j;
    float a = 0.f;
    #pragma unroll
    for (int p = 0; p < KS2; ++p) a += outp[((size_t)p * NSEQ + s) * HID + c];
    v[j] = a;
  }
  float ss = v[0]*v[0] + v[1]*v[1] + v[2]*v[2];
  #pragma unroll
  for (int off = 32; off > 0; off >>= 1) ss += __shfl_down(ss, off, 64);
  __shared__ float wsum[4];
  if ((tid & 63) == 0) wsum[tid >> 6] = ss;
  __syncthreads();
  const float tot = wsum[0] + wsum[1] + wsum[2] + wsum[3];
  const float scale = 1.0f / fmaxf(sqrtf(tot), 1e-12f);
  #pragma unroll
  for (int j = 0; j < 3; ++j) out[(size_t)s * HID + tid + 256 * j] = v[j] * scale;
}

extern "C" void kernel_launch(void* const* d_in, const int* in_sizes, int n_in,
                              void* d_out, int out_size, void* d_ws, size_t ws_size,
                              hipStream_t stream) {
  const float* x    = (const float*)d_in[0];  // [65536, 768]
  const int*   lens = (const int*)d_in[1];    // [128]
  const float* W1   = (const float*)d_in[2];  // [3072, 768]
  const float* W2   = (const float*)d_in[3];  // [768, 3072]
  float* out = (float*)d_out;                 // [128, 768]

  float* pooled = (float*)d_ws;                       // 128*768
  float* h1p    = pooled + NSEQ * HID;                // 8 * 128*3072
  float* h1     = h1p + (size_t)KS1 * NSEQ * FFD;     // 128*3072
  float* outp   = h1 + (size_t)NSEQ * FFD;            // 24 * 128*768

  hipMemsetAsync(pooled, 0, (size_t)NSEQ * HID * sizeof(float), stream);

  pool_kernel<<<NPCH, 192, 0, stream>>>(x, lens, pooled);
  gemm_nt<<<dim3(FFD / 32, KS1), 256, 0, stream>>>(pooled, W1, h1p, FFD, HID, KCH1);
  reduce_h1<<<NSEQ * FFD / 4 / 256, 256, 0, stream>>>(h1p, h1);
  gemm_nt<<<dim3(HID / 32, KS2), 256, 0, stream>>>(h1, W2, outp, HID, FFD, KCH2);
  norm_kernel<<<NSEQ, 256, 0, stream>>>(outp, out);
}